// Round 2
// baseline (9240.501 us; speedup 1.0000x reference)
//
#include <hip/hip_runtime.h>

#define BB 32
#define SEQ 40
#define TT 40
#define EE 512
#define HH 1024

typedef unsigned short bfu;

__device__ __forceinline__ float b2f(bfu u) {
  unsigned int x = ((unsigned int)u) << 16; float f;
  __builtin_memcpy(&f, &x, 4); return f;
}
__device__ __forceinline__ bfu f2b(float f) {
  unsigned int x; __builtin_memcpy(&x, &f, 4);
  unsigned int r = (x + 0x7fffu + ((x >> 16) & 1u)) >> 16;
  return (bfu)r;
}
__device__ __forceinline__ float sigm(float x) { return 1.f / (1.f + expf(-x)); }

// dual-dtype loads: isbf=1 -> bf16, 0 -> fp32
__device__ __forceinline__ float ldg1(const void* b, long i, int isbf) {
  return isbf ? b2f(((const bfu*)b)[i]) : ((const float*)b)[i];
}
__device__ __forceinline__ float4 ldg4(const void* b, long i, int isbf) {
  if (isbf) {
    ushort4 u = *(const ushort4*)((const bfu*)b + i);
    return make_float4(b2f(u.x), b2f(u.y), b2f(u.z), b2f(u.w));
  }
  return *(const float4*)((const float*)b + i);
}

// ---------------- workspace offsets (floats) ----------------
#define OFF_MIXW   0L
#define OFF_FLAG   8L
#define OFF_DECB   16L
#define OFF_HF     544L
#define OFF_HB     (OFF_HF + 32768L)
#define OFF_ENCIN  (OFF_HB + 32768L)            // [1280,1024]
#define OFF_GIF    (OFF_ENCIN + 1310720L)       // [1280,3072] rows b*S+s
#define OFF_GIB    (OFF_GIF + 3932160L)
#define OFF_CTX    (OFF_GIB + 3932160L)         // [B,S,2H]
#define OFF_GHP    (OFF_CTX + 2621440L)         // 8 x [32,3072] partials
#define OFF_QP     (OFF_GHP + 786432L)          // 4 x [32,1024] partials
#define OFF_CMEAN  (OFF_QP + 131072L)           // [32,2048]
#define OFF_CACHE  (OFF_CMEAN + 65536L)         // [1280,1024]
#define OFF_YEMB   (OFF_CACHE + 1310720L)       // [1280,512] rows t*B+b
#define OFF_GI1    (OFF_YEMB + 655360L)         // [1280,3072] rows t*B+b
#define OFF_HDEC   (OFF_GI1 + 3932160L)
#define OFF_H1     (OFF_HDEC + 32768L)
#define OFF_OUTS   (OFF_H1 + 32768L)            // [1280,1024]
#define OFF_ATT    (OFF_OUTS + 1310720L)        // [1280,2048]
#define OFF_LOGITS (OFF_ATT + 2621440L)         // [1280,512]
#define WS_FLOATS  (OFF_LOGITS + 655360L)

// ---------------- prep: dtype probe, zero h, mix softmax, combined dec bias ----------------
__global__ __launch_bounds__(256) void prep_kernel(
    const void* probe, const void* mix_w, const void* mix_gamma,
    const void* dbi, const void* dbh, const void* dbc, float* ws) {
  __shared__ int sflag;
  if (blockIdx.x == 0) {
    if (threadIdx.x == 0) {
      // bf16 data: every even ushort is a valid small bf16 (|v|<0.08).
      // fp32 data: even ushorts are mantissa garbage -> decode >=1 / NaN w.p. ~0.5 each.
      const unsigned short* u = (const unsigned short*)probe;
      int ok = 1;
      for (int i = 0; i < 256; i += 2) {
        float v = b2f(u[i]);
        if (!(v < 1.0f && v > -1.0f)) ok = 0;  // NaN also fails -> fp32
      }
      sflag = ok;
      *(int*)(ws + OFF_FLAG) = ok;
    }
    __syncthreads();
    int isbf = sflag;
    for (int e = threadIdx.x; e < 512; e += 256)
      ws[OFF_DECB + e] = ldg1(dbi, e, isbf) + ldg1(dbh, e, isbf) + ldg1(dbc, e, isbf);
    if (threadIdx.x == 0) {
      float w[6], mx = -1e30f;
      for (int i = 0; i < 6; ++i) { w[i] = ldg1(mix_w, i, isbf); mx = fmaxf(mx, w[i]); }
      float s = 0.f;
      for (int i = 0; i < 6; ++i) { w[i] = expf(w[i] - mx); s += w[i]; }
      float g = ldg1(mix_gamma, 0, isbf);
      for (int i = 0; i < 6; ++i) ws[OFF_MIXW + i] = g * w[i] / s;
    }
  }
  int idx = blockIdx.x * 256 + threadIdx.x;
  if (idx < 65536) ws[OFF_HF + idx] = 0.f;
}

// ---------------- embedding gathers (width 512) ----------------
__global__ __launch_bounds__(256) void gather_kernel(
    const void* table, const int* idx, float* dst, int ld, const int* flagp) {
  int isbf = *flagp;
  int i = blockIdx.x * 256 + threadIdx.x;  // rows*512
  int r = i >> 9, c = i & 511;
  dst[(long)r * ld + c] = ldg1(table, (long)idx[r] * 512 + c, isbf);
}

// ---------------- generic big GEMM: C = act( sum_seg scale*A_seg@B_seg^T + bias ) ----------------
struct GemmP {
  const void* A[6]; const void* B[6]; int K[6]; const float* sc[6]; int abf[6];
  int nseg, N, act, remap, obf, ldc;
  const float* bias;
  const int* flag;
  void* out;
};

__global__ __launch_bounds__(256) void gemm_f32(GemmP p) {
  __shared__ float As[16][68];
  __shared__ float Bs[16][68];
  int isbf = *p.flag;
  int tid = threadIdx.x;
  int m0 = blockIdx.x * 64, n0 = blockIdx.y * 64;
  float acc[4][4];
#pragma unroll
  for (int i = 0; i < 4; ++i)
#pragma unroll
    for (int j = 0; j < 4; ++j) acc[i][j] = 0.f;
  int lm = tid >> 2, lc = (tid & 3) << 2;
  int tmq = (tid >> 4) << 2, tnq = (tid & 15) << 2;
  for (int sg = 0; sg < p.nseg; ++sg) {
    int K = p.K[sg];
    float scale = p.sc[sg] ? *(p.sc[sg]) : 1.f;
    int amode = p.abf[sg] ? isbf : 0;  // ws buffers are always fp32
    int ktiles = (K + 15) >> 4;
    for (int kt = 0; kt < ktiles; ++kt) {
      int k0 = kt << 4;
      long abase = (long)(m0 + lm) * K + k0 + lc;
      float4 av;
      if (k0 + lc + 4 <= K) av = ldg4(p.A[sg], abase, amode);
      else {
        av.x = (k0 + lc + 0 < K) ? ldg1(p.A[sg], abase + 0, amode) : 0.f;
        av.y = (k0 + lc + 1 < K) ? ldg1(p.A[sg], abase + 1, amode) : 0.f;
        av.z = (k0 + lc + 2 < K) ? ldg1(p.A[sg], abase + 2, amode) : 0.f;
        av.w = (k0 + lc + 3 < K) ? ldg1(p.A[sg], abase + 3, amode) : 0.f;
      }
      As[lc + 0][lm] = av.x * scale; As[lc + 1][lm] = av.y * scale;
      As[lc + 2][lm] = av.z * scale; As[lc + 3][lm] = av.w * scale;
      long bbase = (long)(n0 + lm) * K + k0 + lc;
      float4 bv;
      if (k0 + lc + 4 <= K) bv = ldg4(p.B[sg], bbase, isbf);
      else {
        bv.x = (k0 + lc + 0 < K) ? ldg1(p.B[sg], bbase + 0, isbf) : 0.f;
        bv.y = (k0 + lc + 1 < K) ? ldg1(p.B[sg], bbase + 1, isbf) : 0.f;
        bv.z = (k0 + lc + 2 < K) ? ldg1(p.B[sg], bbase + 2, isbf) : 0.f;
        bv.w = (k0 + lc + 3 < K) ? ldg1(p.B[sg], bbase + 3, isbf) : 0.f;
      }
      Bs[lc + 0][lm] = bv.x; Bs[lc + 1][lm] = bv.y;
      Bs[lc + 2][lm] = bv.z; Bs[lc + 3][lm] = bv.w;
      __syncthreads();
#pragma unroll
      for (int k = 0; k < 16; ++k) {
        float4 a = *(const float4*)&As[k][tmq];
        float4 b = *(const float4*)&Bs[k][tnq];
        acc[0][0] += a.x * b.x; acc[0][1] += a.x * b.y; acc[0][2] += a.x * b.z; acc[0][3] += a.x * b.w;
        acc[1][0] += a.y * b.x; acc[1][1] += a.y * b.y; acc[1][2] += a.y * b.z; acc[1][3] += a.y * b.w;
        acc[2][0] += a.z * b.x; acc[2][1] += a.z * b.y; acc[2][2] += a.z * b.z; acc[2][3] += a.z * b.w;
        acc[3][0] += a.w * b.x; acc[3][1] += a.w * b.y; acc[3][2] += a.w * b.z; acc[3][3] += a.w * b.w;
      }
      __syncthreads();
    }
  }
  int om = p.obf ? isbf : 0;
#pragma unroll
  for (int i = 0; i < 4; ++i) {
    int m = m0 + tmq + i;
    float4 r = make_float4(acc[i][0], acc[i][1], acc[i][2], acc[i][3]);
    if (p.bias) {
      const float* bp = p.bias + n0 + tnq;
      r.x += bp[0]; r.y += bp[1]; r.z += bp[2]; r.w += bp[3];
    }
    if (p.act) { r.x = tanhf(r.x); r.y = tanhf(r.y); r.z = tanhf(r.z); r.w = tanhf(r.w); }
    long orow = p.remap ? (long)((m & 31) * TT + (m >> 5)) : (long)m;
    long base = orow * (long)p.ldc + n0 + tnq;
    if (om) {
      ushort4 u; u.x = f2b(r.x); u.y = f2b(r.y); u.z = f2b(r.z); u.w = f2b(r.w);
      *(ushort4*)((bfu*)p.out + base) = u;
    } else {
      *(float4*)((float*)p.out + base) = r;
    }
  }
}

// ---------------- small-M (32) split-K GEMM for recurrent matmuls ----------------
// grid: (N/64, KS, nprob). out[((p*KS+ky)*32+m)*N + n] partials. A is ws fp32, B external.
__global__ __launch_bounds__(256) void gru_gemm(
    const float* A0, const void* B0, int K0,
    const float* A1, const void* B1, int K1,
    float* out, int N, int KS, const int* flagp) {
  __shared__ float As[16][36];
  __shared__ float Bs[16][68];
  int isbf = *flagp;
  int tid = threadIdx.x;
  int p = blockIdx.z;
  const float* A = p ? A1 : A0;
  const void* Bw = p ? B1 : B0;
  int K = p ? K1 : K0;
  int kslice = K / KS;
  int kbeg = blockIdx.y * kslice;
  int n0 = blockIdx.x * 64;
  float acc[2][4];
#pragma unroll
  for (int i = 0; i < 2; ++i)
#pragma unroll
    for (int j = 0; j < 4; ++j) acc[i][j] = 0.f;
  int lm = tid >> 2, lc = (tid & 3) << 2;
  int tn4 = (tid & 15) << 2, tm2 = (tid >> 4) << 1;
  int ktiles = kslice >> 4;
  for (int kt = 0; kt < ktiles; ++kt) {
    int k0 = kbeg + (kt << 4);
    if (tid < 128) {
      const float* Af = A + (long)lm * K + k0 + lc;
      float4 av = *(const float4*)Af;
      As[lc + 0][lm] = av.x; As[lc + 1][lm] = av.y;
      As[lc + 2][lm] = av.z; As[lc + 3][lm] = av.w;
    }
    {
      float4 bv = ldg4(Bw, (long)(n0 + lm) * K + k0 + lc, isbf);
      Bs[lc + 0][lm] = bv.x; Bs[lc + 1][lm] = bv.y;
      Bs[lc + 2][lm] = bv.z; Bs[lc + 3][lm] = bv.w;
    }
    __syncthreads();
#pragma unroll
    for (int k = 0; k < 16; ++k) {
      float4 b = *(const float4*)&Bs[k][tn4];
      float2 a = *(const float2*)&As[k][tm2];
      acc[0][0] += a.x * b.x; acc[0][1] += a.x * b.y; acc[0][2] += a.x * b.z; acc[0][3] += a.x * b.w;
      acc[1][0] += a.y * b.x; acc[1][1] += a.y * b.y; acc[1][2] += a.y * b.z; acc[1][3] += a.y * b.w;
    }
    __syncthreads();
  }
  long obase = (long)(p * KS + blockIdx.y) * 32;
#pragma unroll
  for (int r2 = 0; r2 < 2; ++r2) {
    float4 v = make_float4(acc[r2][0], acc[r2][1], acc[r2][2], acc[r2][3]);
    *(float4*)&out[(obase + tm2 + r2) * (long)N + n0 + tn4] = v;
  }
}

// ---------------- encoder gates (both directions) ----------------
__global__ __launch_bounds__(256) void enc_gates(
    const float* ghp, const float* gi_f, const float* gi_b,
    const void* ef_bih, const void* ef_bhh, const void* eb_bih, const void* eb_bhh,
    float* h_f, float* h_b, float* ctx, int t, const int* flagp) {
  int isbf = *flagp;
  int idx = blockIdx.x * 256 + threadIdx.x;  // 65536
  int dir = idx >> 15;
  int rem = idx & 32767;
  int b = rem >> 10, u = rem & 1023;
  const float* gi; const void *bih, *bhh; float* h; int s;
  if (dir == 0) { gi = gi_f + (long)(b * SEQ + t) * 3072; bih = ef_bih; bhh = ef_bhh; h = h_f; s = t; }
  else { gi = gi_b + (long)(b * SEQ + (SEQ - 1 - t)) * 3072; bih = eb_bih; bhh = eb_bhh; h = h_b; s = SEQ - 1 - t; }
  float ghr = 0.f, ghz = 0.f, ghn = 0.f;
  for (int ks = 0; ks < 4; ++ks) {
    const float* g = ghp + (long)((dir * 4 + ks) * 32 + b) * 3072;
    ghr += g[u]; ghz += g[1024 + u]; ghn += g[2048 + u];
  }
  ghr += ldg1(bhh, u, isbf); ghz += ldg1(bhh, 1024 + u, isbf); ghn += ldg1(bhh, 2048 + u, isbf);
  float gir = gi[u] + ldg1(bih, u, isbf);
  float giz = gi[1024 + u] + ldg1(bih, 1024 + u, isbf);
  float gin = gi[2048 + u] + ldg1(bih, 2048 + u, isbf);
  float r = sigm(gir + ghr), z = sigm(giz + ghz);
  float n = tanhf(gin + r * ghn);
  float hv = h[rem];
  float hn2 = (1.f - z) * n + z * hv;
  h[rem] = hn2;
  ctx[((long)((b * SEQ + s) * 2 + dir) << 10) + u] = hn2;
}

// ---------------- bridge ----------------
__global__ __launch_bounds__(256) void bridge_mean(const float* ctx, const int* xs, float* cmean) {
  int b = blockIdx.x, tid = threadIdx.x;
  float cnt = 0.f;
  for (int s = 0; s < SEQ; ++s) cnt += (xs[b * SEQ + s] != 0) ? 1.f : 0.f;
  for (int c = tid; c < 2048; c += 256) {
    float a = 0.f;
    for (int s = 0; s < SEQ; ++s)
      if (xs[b * SEQ + s] != 0) a += ctx[((long)(b * SEQ + s) << 11) + c];
    cmean[((long)b << 11) + c] = a / cnt;
  }
}

__global__ __launch_bounds__(256) void bridge_fin(const float* qp, const void* br_b, float* hdec,
                                                  const int* flagp) {
  int isbf = *flagp;
  int idx = blockIdx.x * 256 + threadIdx.x;  // 32768
  int b = idx >> 10, u = idx & 1023;
  float a = ldg1(br_b, u, isbf);
  for (int ks = 0; ks < 4; ++ks) a += qp[((long)(ks * 32 + b) << 10) + u];
  hdec[idx] = tanhf(a);
}

// ---------------- decoder gates ----------------
__global__ __launch_bounds__(256) void dec_gates1(
    const float* ghp, const float* gi1_t, const void* bih, const void* bhh,
    const float* hprev, float* h1, const int* flagp) {
  int isbf = *flagp;
  int idx = blockIdx.x * 256 + threadIdx.x;  // 32768
  int b = idx >> 10, u = idx & 1023;
  float ghr = 0.f, ghz = 0.f, ghn = 0.f;
  for (int ks = 0; ks < 4; ++ks) {
    const float* g = ghp + (long)(ks * 32 + b) * 3072;
    ghr += g[u]; ghz += g[1024 + u]; ghn += g[2048 + u];
  }
  ghr += ldg1(bhh, u, isbf); ghz += ldg1(bhh, 1024 + u, isbf); ghn += ldg1(bhh, 2048 + u, isbf);
  const float* gi = gi1_t + (long)b * 3072;
  float gir = gi[u] + ldg1(bih, u, isbf);
  float giz = gi[1024 + u] + ldg1(bih, 1024 + u, isbf);
  float gin = gi[2048 + u] + ldg1(bih, 2048 + u, isbf);
  float r = sigm(gir + ghr), z = sigm(giz + ghz);
  float n = tanhf(gin + r * ghn);
  h1[idx] = (1.f - z) * n + z * hprev[idx];
}

__global__ __launch_bounds__(256) void dec_gates2(
    const float* ghp, const void* bih, const void* bhh,
    const float* h1, float* hdec, float* outs_t, const int* flagp) {
  int isbf = *flagp;
  int idx = blockIdx.x * 256 + threadIdx.x;  // 32768
  int b = idx >> 10, u = idx & 1023;
  float gir = 0.f, giz = 0.f, gin = 0.f, ghr = 0.f, ghz = 0.f, ghn = 0.f;
  for (int ks = 0; ks < 4; ++ks) {
    const float* g = ghp + (long)(ks * 32 + b) * 3072;
    gir += g[u]; giz += g[1024 + u]; gin += g[2048 + u];
    const float* g2 = ghp + (long)((4 + ks) * 32 + b) * 3072;
    ghr += g2[u]; ghz += g2[1024 + u]; ghn += g2[2048 + u];
  }
  gir += ldg1(bih, u, isbf); giz += ldg1(bih, 1024 + u, isbf); gin += ldg1(bih, 2048 + u, isbf);
  ghr += ldg1(bhh, u, isbf); ghz += ldg1(bhh, 1024 + u, isbf); ghn += ldg1(bhh, 2048 + u, isbf);
  float r = sigm(gir + ghr), z = sigm(giz + ghz);
  float n = tanhf(gin + r * ghn);
  float hv = h1[idx];
  float h2 = (1.f - z) * n + z * hv;
  hdec[idx] = h2;
  outs_t[idx] = h2;
}

// ---------------- attention (per batch row) ----------------
__global__ __launch_bounds__(256) void attention_kernel(
    const float* qp, const void* att_bq, const float* cache, const void* att_v,
    const float* ctx, const int* xs, float* attns_t, const int* flagp) {
  __shared__ float qsh[1024], vsh[1024], ssh[SEQ];
  int isbf = *flagp;
  int b = blockIdx.x, tid = threadIdx.x;
  for (int h = tid; h < 1024; h += 256) {
    float q = ldg1(att_bq, h, isbf);
    for (int ks = 0; ks < 4; ++ks) q += qp[((long)(ks * 32 + b) << 10) + h];
    qsh[h] = q;
    vsh[h] = ldg1(att_v, h, isbf);
  }
  __syncthreads();
  int lane = tid & 63, wv = tid >> 6;
  for (int s = wv; s < SEQ; s += 4) {
    const float* cr = cache + ((long)(b * SEQ + s) << 10);
    float p = 0.f;
    for (int h = lane; h < 1024; h += 64)
      p += tanhf(qsh[h] + cr[h]) * vsh[h];
    for (int off = 32; off; off >>= 1) p += __shfl_down(p, off, 64);
    if (lane == 0) ssh[s] = (xs[b * SEQ + s] == 0) ? -1e9f : p;
  }
  __syncthreads();
  if (tid < 64) {
    float x = (tid < SEQ) ? ssh[tid] : -3.4e38f;
    float m = x;
    for (int off = 32; off; off >>= 1) m = fmaxf(m, __shfl_down(m, off, 64));
    m = __shfl(m, 0, 64);
    float e = (tid < SEQ) ? expf(x - m) : 0.f;
    float ssum = e;
    for (int off = 32; off; off >>= 1) ssum += __shfl_down(ssum, off, 64);
    ssum = __shfl(ssum, 0, 64);
    if (tid < SEQ) ssh[tid] = e / ssum;
  }
  __syncthreads();
  for (int c = tid; c < 2048; c += 256) {
    float a = 0.f;
    for (int s = 0; s < SEQ; ++s)
      a += ssh[s] * ctx[((long)(b * SEQ + s) << 11) + c];
    attns_t[((long)b << 11) + c] = a;
  }
}

// ---------------- in-place log-softmax over VT=32000 (dtype per flag) ----------------
__global__ __launch_bounds__(256) void logsoftmax_kernel(void* out, const int* flagp) {
  __shared__ float red[256];
  int isbf = *flagp;
  long row = blockIdx.x;
  bfu* xb = (bfu*)out + row * 32000L;
  float* xf = (float*)out + row * 32000L;
  int tid = threadIdx.x;
  float m = -3.4e38f;
  for (int v = tid; v < 32000; v += 256) if (v) {
    float val = isbf ? b2f(xb[v]) : xf[v];
    m = fmaxf(m, val);
  }
  red[tid] = m; __syncthreads();
  for (int s2 = 128; s2; s2 >>= 1) {
    if (tid < s2) red[tid] = fmaxf(red[tid], red[tid + s2]);
    __syncthreads();
  }
  m = red[0]; __syncthreads();
  float s = 0.f;
  for (int v = tid; v < 32000; v += 256) if (v) {
    float val = isbf ? b2f(xb[v]) : xf[v];
    s += expf(val - m);
  }
  red[tid] = s; __syncthreads();
  for (int s2 = 128; s2; s2 >>= 1) {
    if (tid < s2) red[tid] += red[tid + s2];
    __syncthreads();
  }
  float lse = m + logf(red[0]);
  for (int v = tid; v < 32000; v += 256) {
    float val = v ? (isbf ? b2f(xb[v]) : xf[v]) : -1e9f;
    float res = val - lse;
    if (isbf) xb[v] = f2b(res); else xf[v] = res;
  }
}

// ---------------- host ----------------
static void launch_gemm(hipStream_t st, const GemmP& p) {
  dim3 g(1280 / 64, p.N / 64);
  hipLaunchKernelGGL(gemm_f32, g, dim3(256), 0, st, p);
}

extern "C" void kernel_launch(void* const* d_in, const int* in_sizes, int n_in,
                              void* d_out, int out_size, void* d_ws, size_t ws_size,
                              hipStream_t stream) {
  if (n_in < 48) return;
  if (ws_size < (size_t)WS_FLOATS * 4) return;
  const int* xs = (const int*)d_in[0];
  const int* y = (const int*)d_in[1];
  const void* syn_emb = d_in[3];
  const void* syn_l0 = d_in[4];
  const void* syn_l1 = d_in[5];
  const void* syn_l2 = d_in[6];
  const void* syn_dep = d_in[7];
  const void* syn_head = d_in[8];
  const void* src_emb = d_in[9];
  const void* tgt_emb = d_in[10];
  const void* W_semb = d_in[11];
  const void* W_sl0 = d_in[12];
  const void* W_sl1 = d_in[13];
  const void* W_sl2 = d_in[14];
  const void* W_sdep = d_in[15];
  const void* W_shead = d_in[16];
  const void* mix_w = d_in[17];
  const void* mix_gamma = d_in[18];
  const void* ef_Wih = d_in[19];
  const void* ef_Whh = d_in[20];
  const void* ef_bih = d_in[21];
  const void* ef_bhh = d_in[22];
  const void* eb_Wih = d_in[23];
  const void* eb_Whh = d_in[24];
  const void* eb_bih = d_in[25];
  const void* eb_bhh = d_in[26];
  const void* br_W = d_in[27];
  const void* br_b = d_in[28];
  const void* g1_Wih = d_in[29];
  const void* g1_Whh = d_in[30];
  const void* g1_bih = d_in[31];
  const void* g1_bhh = d_in[32];
  const void* att_Wq = d_in[33];
  const void* att_bq = d_in[34];
  const void* att_Wk = d_in[35];
  const void* att_v = d_in[36];
  const void* g2_Wih = d_in[37];
  const void* g2_Whh = d_in[38];
  const void* g2_bih = d_in[39];
  const void* g2_bhh = d_in[40];
  const void* dec_Wi = d_in[41];
  const void* dec_bi = d_in[42];
  const void* dec_Wh = d_in[43];
  const void* dec_bh = d_in[44];
  const void* dec_Wc = d_in[45];
  const void* dec_bc = d_in[46];
  const void* gen_W = d_in[47];

  float* ws = (float*)d_ws;
  float* w_mixw = ws + OFF_MIXW;
  float* w_decb = ws + OFF_DECB;
  const int* dflag = (const int*)(ws + OFF_FLAG);
  float* h_f = ws + OFF_HF;
  float* h_b = ws + OFF_HB;
  float* enc_in = ws + OFF_ENCIN;
  float* gi_f = ws + OFF_GIF;
  float* gi_b = ws + OFF_GIB;
  float* ctx = ws + OFF_CTX;
  float* ghp = ws + OFF_GHP;
  float* qp = ws + OFF_QP;
  float* cmean = ws + OFF_CMEAN;
  float* cache = ws + OFF_CACHE;
  float* yemb = ws + OFF_YEMB;
  float* gi1 = ws + OFF_GI1;
  float* hdec = ws + OFF_HDEC;
  float* h1 = ws + OFF_H1;
  float* outs = ws + OFF_OUTS;
  float* attns = ws + OFF_ATT;
  float* logits = ws + OFF_LOGITS;

  dim3 blk(256);

  // prep (dtype probe first) + embeddings
  hipLaunchKernelGGL(prep_kernel, dim3(256), blk, 0, stream,
                     src_emb, mix_w, mix_gamma, dec_bi, dec_bh, dec_bc, ws);
  hipLaunchKernelGGL(gather_kernel, dim3(2560), blk, 0, stream, src_emb, xs, enc_in, 1024, dflag);
  hipLaunchKernelGGL(gather_kernel, dim3(2560), blk, 0, stream, tgt_emb, y, yemb, 512, dflag);

  // scalar mix -> enc_in[:, 512:1024]
  {
    GemmP p{};
    const void* As[6] = {syn_emb, syn_l0, syn_l1, syn_l2, syn_dep, syn_head};
    const void* Bsx[6] = {W_semb, W_sl0, W_sl1, W_sl2, W_sdep, W_shead};
    int Ks[6] = {100, 800, 800, 800, 600, 600};
    for (int i = 0; i < 6; ++i) {
      p.A[i] = As[i]; p.B[i] = Bsx[i]; p.K[i] = Ks[i];
      p.sc[i] = w_mixw + i; p.abf[i] = 1;
    }
    p.nseg = 6; p.N = 512; p.act = 0; p.remap = 0; p.obf = 0;
    p.ldc = 1024; p.bias = nullptr; p.flag = dflag; p.out = enc_in + 512;
    launch_gemm(stream, p);
  }

  // encoder gi (both directions, batched over positions)
  {
    GemmP p{};
    p.A[0] = enc_in; p.B[0] = ef_Wih; p.K[0] = 1024; p.sc[0] = nullptr; p.abf[0] = 0;
    p.nseg = 1; p.N = 3072; p.act = 0; p.remap = 0; p.obf = 0;
    p.ldc = 3072; p.bias = nullptr; p.flag = dflag; p.out = gi_f;
    launch_gemm(stream, p);
    p.B[0] = eb_Wih; p.out = gi_b;
    launch_gemm(stream, p);
  }

  // encoder recurrence
  for (int t = 0; t < SEQ; ++t) {
    hipLaunchKernelGGL(gru_gemm, dim3(48, 4, 2), blk, 0, stream,
                       h_f, ef_Whh, 1024, h_b, eb_Whh, 1024, ghp, 3072, 4, dflag);
    hipLaunchKernelGGL(enc_gates, dim3(256), blk, 0, stream,
                       ghp, gi_f, gi_b, ef_bih, ef_bhh, eb_bih, eb_bhh,
                       h_f, h_b, ctx, t, dflag);
  }

  // bridge -> hdec
  hipLaunchKernelGGL(bridge_mean, dim3(32), blk, 0, stream, ctx, xs, cmean);
  hipLaunchKernelGGL(gru_gemm, dim3(16, 4, 1), blk, 0, stream,
                     cmean, br_W, 2048, (const float*)nullptr, (const void*)nullptr, 0,
                     qp, 1024, 4, dflag);
  hipLaunchKernelGGL(bridge_fin, dim3(128), blk, 0, stream, qp, br_b, hdec, dflag);

  // attention key cache
  {
    GemmP p{};
    p.A[0] = ctx; p.B[0] = att_Wk; p.K[0] = 2048; p.sc[0] = nullptr; p.abf[0] = 0;
    p.nseg = 1; p.N = 1024; p.act = 0; p.remap = 0; p.obf = 0;
    p.ldc = 1024; p.bias = nullptr; p.flag = dflag; p.out = cache;
    launch_gemm(stream, p);
  }

  // decoder gi1 (batched over T)
  {
    GemmP p{};
    p.A[0] = yemb; p.B[0] = g1_Wih; p.K[0] = 512; p.sc[0] = nullptr; p.abf[0] = 0;
    p.nseg = 1; p.N = 3072; p.act = 0; p.remap = 0; p.obf = 0;
    p.ldc = 3072; p.bias = nullptr; p.flag = dflag; p.out = gi1;
    launch_gemm(stream, p);
  }

  // decoder recurrence
  for (int t = 0; t < TT; ++t) {
    float* gi1_t = gi1 + (long)t * 32 * 3072;
    float* attns_t = attns + (long)t * 32 * 2048;
    float* outs_t = outs + (long)t * 32 * 1024;
    hipLaunchKernelGGL(gru_gemm, dim3(48, 4, 1), blk, 0, stream,
                       hdec, g1_Whh, 1024, (const float*)nullptr, (const void*)nullptr, 0,
                       ghp, 3072, 4, dflag);
    hipLaunchKernelGGL(dec_gates1, dim3(128), blk, 0, stream,
                       ghp, gi1_t, g1_bih, g1_bhh, hdec, h1, dflag);
    hipLaunchKernelGGL(gru_gemm, dim3(16, 4, 1), blk, 0, stream,
                       h1, att_Wq, 1024, (const float*)nullptr, (const void*)nullptr, 0,
                       qp, 1024, 4, dflag);
    hipLaunchKernelGGL(attention_kernel, dim3(32), blk, 0, stream,
                       qp, att_bq, cache, att_v, ctx, xs, attns_t, dflag);
    hipLaunchKernelGGL(gru_gemm, dim3(48, 4, 2), blk, 0, stream,
                       attns_t, g2_Wih, 2048, h1, g2_Whh, 1024, ghp, 3072, 4, dflag);
    hipLaunchKernelGGL(dec_gates2, dim3(128), blk, 0, stream,
                       ghp, g2_bih, g2_bhh, h1, hdec, outs_t, dflag);
  }

  // pre-logits: tanh(yemb@Wi^T + outs@Wh^T + attns@Wc^T + combined bias)
  {
    GemmP p{};
    p.A[0] = yemb; p.B[0] = dec_Wi; p.K[0] = 512; p.sc[0] = nullptr; p.abf[0] = 0;
    p.A[1] = outs; p.B[1] = dec_Wh; p.K[1] = 1024; p.sc[1] = nullptr; p.abf[1] = 0;
    p.A[2] = attns; p.B[2] = dec_Wc; p.K[2] = 2048; p.sc[2] = nullptr; p.abf[2] = 0;
    p.nseg = 3; p.N = 512; p.act = 1; p.remap = 0; p.obf = 0;
    p.ldc = 512; p.bias = w_decb; p.flag = dflag; p.out = logits;
    launch_gemm(stream, p);
  }

  // generator: gscores -> d_out (dtype per flag), rows remapped [t*B+b] -> [b*T+t]
  {
    GemmP p{};
    p.A[0] = logits; p.B[0] = gen_W; p.K[0] = 512; p.sc[0] = nullptr; p.abf[0] = 0;
    p.nseg = 1; p.N = 32000; p.act = 0; p.remap = 1; p.obf = 1;
    p.ldc = 32000; p.bias = nullptr; p.flag = dflag; p.out = d_out;
    launch_gemm(stream, p);
  }

  // in-place log-softmax with PAD column = -1e9
  hipLaunchKernelGGL(logsoftmax_kernel, dim3(1280), blk, 0, stream, d_out, dflag);
}